// Round 1
// baseline (96.322 us; speedup 1.0000x reference)
//
#include <hip/hip_runtime.h>
#include <hip/hip_bf16.h>
#include <stdint.h>

// Problem: out = q5( q5(x) @fixedpoint q5(W) + b ), q5(a)=trunc(32a)/32
// x [1024,2048] f32, W [2048,1024] f32, b [1024] f32, out [1024,1024] f32.
//
// Exact reformulation:
//   term(i,j,k) = trunc(ix*iw/32)/32,  ix=trunc(32x), iw=trunc(32W)
//   for |iw|<=1: term = iw * trunc(x) / 32  -> integer GEMM A=trunc(x), B=iw
//   for |iw|>=2 (prob ~1e-3 over whole W): B entry zeroed, exact correction
//   added via corr[i,j] (int32). Epilogue: out = trunc(C + corr + 32b)/32.
// All values are small integers -> exact in bf16 inputs / f32 MFMA accum.

#define M_DIM 1024
#define N_DIM 1024
#define K_DIM 2048
#define MAXBAD 4096

typedef float f32x4 __attribute__((ext_vector_type(4)));
typedef __bf16 bf16x8 __attribute__((ext_vector_type(8)));

// ws layout (bytes):
//  [0,4MB)      Aimg bf16 tiled [M/64][K/64][64 rows][64 k], XOR-swizzled
//  [4MB,8MB)    Bimg bf16 tiled [K/64][N/64][64 cols][64 k], XOR-swizzled
//  [8MB,12MB)   corr int32 [M][N]
//  [12MB]       counter int
//  [12MB+16,..) bad entries (k,j,iw) int triples
#define A_OFF   (0u)
#define B_OFF   (4u << 20)
#define C_OFF   (8u << 20)
#define CNT_OFF (12u << 20)
#define ENT_OFF ((12u << 20) + 16u)

__device__ __forceinline__ unsigned short f2bf(float f) {
    // exact for our small-integer values (low mantissa bits are zero)
    return (unsigned short)(__builtin_bit_cast(unsigned, f) >> 16);
}

__device__ __forceinline__ void gload16(const void* g, void* l) {
    // width-16 global->LDS async copy; LDS dest = wave-uniform base + lane*16
    __builtin_amdgcn_global_load_lds(
        (__attribute__((address_space(1))) void*)(void*)g,
        (__attribute__((address_space(3))) void*)l,
        16, 0, 0);
}

// x -> A image: A[row][k] = bf16(trunc(x)), stored tile-by-tile with the
// st-row XOR swizzle applied so GEMM's linear global_load_lds + swizzled
// ds_read is conflict-free (both-sides-or-neither).
__global__ __launch_bounds__(256) void quant_x_kernel(
    const float* __restrict__ x, unsigned char* __restrict__ Aimg) {
    int g = blockIdx.x * 256 + threadIdx.x;   // 262144 threads, 8 elems each
    int row = g >> 8;
    int k0 = (g & 255) << 3;
    const float* p = x + row * K_DIM + k0;
    float4 v0 = *(const float4*)p;
    float4 v1 = *(const float4*)(p + 4);
    unsigned u0 = (unsigned)f2bf(truncf(v0.x)) | ((unsigned)f2bf(truncf(v0.y)) << 16);
    unsigned u1 = (unsigned)f2bf(truncf(v0.z)) | ((unsigned)f2bf(truncf(v0.w)) << 16);
    unsigned u2 = (unsigned)f2bf(truncf(v1.x)) | ((unsigned)f2bf(truncf(v1.y)) << 16);
    unsigned u3 = (unsigned)f2bf(truncf(v1.z)) | ((unsigned)f2bf(truncf(v1.w)) << 16);
    uint4 o; o.x = u0; o.y = u1; o.z = u2; o.w = u3;
    int mt = row >> 6, r = row & 63, kt = k0 >> 6, kk = k0 & 63;
    unsigned off = (unsigned)(mt * 32 + kt) * 8192u
                 + (unsigned)r * 128u
                 + (((unsigned)kk * 2u) ^ (((unsigned)(r & 7)) << 4));
    *(uint4*)(Aimg + off) = o;
}

// W -> B image (transposed per tile to [col][k]) + bad-entry detection.
__global__ __launch_bounds__(256) void quant_w_kernel(
    const float* __restrict__ W, unsigned char* __restrict__ Bimg,
    int* __restrict__ counter, int* __restrict__ entries) {
    __shared__ unsigned short lt[64][80];   // padded: conflict-light transpose
    int kt = blockIdx.x >> 4;               // K/64 = 32
    int nt = blockIdx.x & 15;               // N/64 = 16
    int t = threadIdx.x;
#pragma unroll
    for (int i = 0; i < 16; ++i) {
        int e = t + i * 256;
        int kk = e >> 6, j = e & 63;
        float wv = W[(kt * 64 + kk) * N_DIM + nt * 64 + j];
        float iwf = truncf(wv * 32.0f);
        unsigned short bw;
        if (iwf > 1.0f || iwf < -1.0f) {
            bw = 0;
            int idx = atomicAdd(counter, 1);
            if (idx < MAXBAD) {
                entries[idx * 3 + 0] = kt * 64 + kk;
                entries[idx * 3 + 1] = nt * 64 + j;
                entries[idx * 3 + 2] = (int)iwf;
            }
        } else {
            bw = f2bf(iwf);
        }
        lt[j][kk] = bw;
    }
    __syncthreads();
    int j = t >> 2, seg = t & 3, k0 = seg * 16;
    unsigned short tmp[16];
#pragma unroll
    for (int q = 0; q < 16; ++q) tmp[q] = lt[j][k0 + q];
    uint4 c0, c1;
    c0.x = (unsigned)tmp[0] | ((unsigned)tmp[1] << 16);
    c0.y = (unsigned)tmp[2] | ((unsigned)tmp[3] << 16);
    c0.z = (unsigned)tmp[4] | ((unsigned)tmp[5] << 16);
    c0.w = (unsigned)tmp[6] | ((unsigned)tmp[7] << 16);
    c1.x = (unsigned)tmp[8] | ((unsigned)tmp[9] << 16);
    c1.y = (unsigned)tmp[10] | ((unsigned)tmp[11] << 16);
    c1.z = (unsigned)tmp[12] | ((unsigned)tmp[13] << 16);
    c1.w = (unsigned)tmp[14] | ((unsigned)tmp[15] << 16);
    unsigned base = (unsigned)(kt * 16 + nt) * 8192u + (unsigned)j * 128u;
    unsigned sw = ((unsigned)(j & 7)) << 4;
    *(uint4*)(Bimg + base + (((unsigned)(2 * k0)) ^ sw)) = c0;
    *(uint4*)(Bimg + base + (((unsigned)(2 * k0 + 16)) ^ sw)) = c1;
}

// Sparse exact correction for |iw|>=2 entries (expected count ~0).
__global__ __launch_bounds__(256) void correct_kernel(
    const float* __restrict__ x, const int* __restrict__ counter,
    const int* __restrict__ entries, int* __restrict__ corr) {
    int n = *counter; if (n > MAXBAD) n = MAXBAD;
    long total = (long)n * M_DIM;
    for (long i = blockIdx.x * 256 + threadIdx.x; i < total; i += 64L * 256L) {
        int e = (int)(i >> 10);
        int row = (int)(i & 1023);
        int k = entries[e * 3 + 0];
        int j = entries[e * 3 + 1];
        int iw = entries[e * 3 + 2];
        int ix = (int)truncf(x[row * K_DIM + k] * 32.0f);
        atomicAdd(&corr[row * N_DIM + j], (ix * iw) / 32);  // C div = trunc
    }
}

// 64x64-tile bf16 MFMA GEMM, K=2048, fused epilogue.
__global__ __launch_bounds__(256) void gemm_kernel(
    const unsigned char* __restrict__ Aimg, const unsigned char* __restrict__ Bimg,
    const int* __restrict__ corr, const float* __restrict__ bias,
    float* __restrict__ out) {
    __shared__ unsigned char As[8192];
    __shared__ unsigned char Bs[8192];
    int bm = blockIdx.x & 15, bn = blockIdx.x >> 4;
    int t = threadIdx.x, lane = t & 63, w = t >> 6;
    int wr = w >> 1, wc = w & 1;            // 2x2 waves of 32x32
    int lr = lane & 15;                     // row/col within a 16-frag
    int lg = lane >> 4;                     // k-group 0..3
    f32x4 acc[2][2] = {};

    const unsigned char* Abase = Aimg + (unsigned)bm * 262144u;  // bm*32 tiles
    const unsigned char* Bbase = Bimg + (unsigned)bn * 8192u;

    for (int kt = 0; kt < 32; ++kt) {
        // stage 8KB A-tile + 8KB B-tile, 2 width-16 calls each per thread
        const unsigned char* ga = Abase + (unsigned)kt * 8192u + (unsigned)(w * 2048 + lane * 16);
        const unsigned char* gb = Bbase + (unsigned)kt * 131072u + (unsigned)(w * 2048 + lane * 16);
        gload16(ga,        As + w * 2048);
        gload16(ga + 1024, As + w * 2048 + 1024);
        gload16(gb,        Bs + w * 2048);
        gload16(gb + 1024, Bs + w * 2048 + 1024);
        __syncthreads();   // compiler emits vmcnt(0) drain before barrier
#pragma unroll
        for (int kh = 0; kh < 2; ++kh) {
            int kb2 = (kh * 32 + lg * 8) * 2;    // byte-of-k within row
            bf16x8 aF[2], bF[2];
#pragma unroll
            for (int mi = 0; mi < 2; ++mi) {
                int r = wr * 32 + mi * 16 + lr;
                unsigned off = (unsigned)r * 128u
                             + (((unsigned)kb2) ^ (((unsigned)(r & 7)) << 4));
                aF[mi] = __builtin_bit_cast(bf16x8, *(const uint4*)(As + off));
            }
#pragma unroll
            for (int ni = 0; ni < 2; ++ni) {
                int c = wc * 32 + ni * 16 + lr;
                unsigned off = (unsigned)c * 128u
                             + (((unsigned)kb2) ^ (((unsigned)(c & 7)) << 4));
                bF[ni] = __builtin_bit_cast(bf16x8, *(const uint4*)(Bs + off));
            }
#pragma unroll
            for (int mi = 0; mi < 2; ++mi)
#pragma unroll
                for (int ni = 0; ni < 2; ++ni)
                    acc[mi][ni] = __builtin_amdgcn_mfma_f32_16x16x32_bf16(
                        aF[mi], bF[ni], acc[mi][ni], 0, 0, 0);
        }
        __syncthreads();
    }

    // epilogue: out = trunc(C + corr + 32b) / 32
#pragma unroll
    for (int mi = 0; mi < 2; ++mi) {
#pragma unroll
        for (int ni = 0; ni < 2; ++ni) {
            int gr0 = bm * 64 + wr * 32 + mi * 16 + lg * 4;
            int gc  = bn * 64 + wc * 32 + ni * 16 + lr;
            float bb = 32.0f * bias[gc];
#pragma unroll
            for (int r = 0; r < 4; ++r) {
                int row = gr0 + r;
                float v = acc[mi][ni][r] + (float)corr[row * N_DIM + gc] + bb;
                out[row * N_DIM + gc] = truncf(v) * 0.03125f;
            }
        }
    }
}

extern "C" void kernel_launch(void* const* d_in, const int* in_sizes, int n_in,
                              void* d_out, int out_size, void* d_ws, size_t ws_size,
                              hipStream_t stream) {
    const float* x = (const float*)d_in[0];
    const float* W = (const float*)d_in[1];
    const float* b = (const float*)d_in[2];
    float* out = (float*)d_out;
    unsigned char* ws = (unsigned char*)d_ws;
    unsigned char* Aimg = ws + A_OFF;
    unsigned char* Bimg = ws + B_OFF;
    int* corr    = (int*)(ws + C_OFF);
    int* counter = (int*)(ws + CNT_OFF);
    int* entries = (int*)(ws + ENT_OFF);

    // zero corr (4MB) + counter (adjacent)
    hipMemsetAsync(ws + C_OFF, 0, (4u << 20) + 32u, stream);
    quant_x_kernel<<<1024, 256, 0, stream>>>(x, Aimg);
    quant_w_kernel<<<512, 256, 0, stream>>>(W, Bimg, counter, entries);
    correct_kernel<<<64, 256, 0, stream>>>(x, counter, entries, corr);
    gemm_kernel<<<256, 256, 0, stream>>>(Aimg, Bimg, corr, b, out);
}